// Round 5
// baseline (177.562 us; speedup 1.0000x reference)
//
#include <hip/hip_runtime.h>
#include <math.h>

// Problem constants
#define BB 4
#define CIN 64
#define COUT 64
#define HH 128
#define WW 128
#define HW (HH*WW)

typedef __attribute__((ext_vector_type(8))) short short8;   // 8 bf16 = 4 VGPRs
typedef __attribute__((ext_vector_type(4))) float f32x4;
typedef __attribute__((ext_vector_type(4))) unsigned int uint4v;

static __device__ __forceinline__ unsigned short f2bf(float f) {
    unsigned int u = __builtin_bit_cast(unsigned int, f);
    u += 0x7fffu + ((u >> 16) & 1u);          // round-to-nearest-even
    return (unsigned short)(u >> 16);
}
static __device__ __forceinline__ float bf2f(unsigned short h) {
    unsigned int u = ((unsigned int)h) << 16;
    return __builtin_bit_cast(float, u);
}

// ---------------------------------------------------------------------------
// K1: wkpack (80 blocks) + bias2 (1 block).  Tiny; everything else moved out.
// ---------------------------------------------------------------------------
__global__ __launch_bounds__(256) void prep_kernel(
        const float* __restrict__ com_w, const float* __restrict__ c2w,
        const float* __restrict__ bias,
        unsigned short* __restrict__ wk2, float* __restrict__ bias2) {
    int id = blockIdx.x, tid = threadIdx.x;
    if (id < 80) {
        int i = id*256 + tid;               // < 20480
        int k = i & 31, oc = (i >> 5) & 31;
        int cc5 = i >> 10;                  // cg*5 + chunk
        int cg = cc5 / 5, ch = cc5 % 5;
        int tap = ch*2 + (k >> 4);
        int c = cg*16 + (k & 15);
        float v = 0.f;
        if (tap < 9 && oc < 27) v = com_w[((size_t)oc*64 + c)*9 + tap];
        wk2[i] = f2bf(v);
    } else if (tid < COUT) {
        float s2 = 0.f;
        for (int o = 0; o < COUT; ++o) s2 += c2w[tid*COUT + o] * bias[o];
        bias2[tid] = s2;
    }
}

// ---------------------------------------------------------------------------
// channel-last bf16 transpose of one (b, 64-px strip): src[b][c][px]->dst[b][px][c]
// ---------------------------------------------------------------------------
static __device__ __forceinline__ void transpose_body(
        const float* __restrict__ srcb, unsigned short* __restrict__ dstb,
        int tb, int tid, float* lt /* 64*65 floats */) {
    int b = tb >> 8;
    int px0 = (tb & 255) * 64;
    const float* src = srcb + (size_t)b*CIN*HW + px0;
    for (int i = tid; i < 4096; i += 256) {
        int c = i >> 6, px = i & 63;
        lt[c*65 + px] = src[(size_t)c*HW + px];
    }
    __syncthreads();
    int q = tid & 3, px = tid >> 2;
    unsigned short* dst = dstb + ((size_t)b*HW + px0 + px)*64 + q*16;
    #pragma unroll
    for (int s = 0; s < 2; ++s) {
        short8 pk;
        #pragma unroll
        for (int j = 0; j < 8; ++j)
            pk[j] = (short)f2bf(lt[(q*16 + s*8 + j)*65 + px]);
        *(short8*)(dst + s*8) = pk;
    }
}

// ---------------------------------------------------------------------------
// w2 with INLINE fvec (wave-reduced): W2b[b][p][o2][c] bf16 (MFMA A layout)
// v5: store UNSWIZZLED again — dcn reads A-frags directly from global
// (L2-hot under XCD binding), no LDS staging, so no swizzle consumer.
// ---------------------------------------------------------------------------
static __device__ __forceinline__ void w2_body(
        int wid, int tid, const float* __restrict__ weight,
        const float* __restrict__ c2w, const float* __restrict__ c1w,
        const float* __restrict__ fea,
        unsigned short* __restrict__ w2b, float* c2s, float* wcol) {
    int o2 = tid & 63, ci = tid >> 6;
    int lane = tid & 63;
    int bp = wid >> 4;
    int c_base = (wid & 15)*4;
    int p = bp % 9, b = bp / 9;
    int c = c_base + ci;

    // inline fvec[b][c] for this wave's c: 4 MAC/lane + wave reduce
    float part = 0.f;
    #pragma unroll
    for (int s = 0; s < 4; ++s)
        part += c1w[c*(4*CIN) + lane + s*64] * fea[b*(4*CIN) + lane + s*64];
    #pragma unroll
    for (int off = 32; off; off >>= 1) part += __shfl_down(part, off);
    float fv = __shfl(part, 0);

    for (int idx = tid; idx < 4096; idx += 256) {
        int o2r = idx >> 6, oc = idx & 63;
        c2s[oc*65 + o2r] = c2w[idx];
    }
    {
        int o = tid & 63, cw = tid >> 6;
        wcol[cw*64 + o] = weight[(o*CIN + (c_base + cw))*9 + p];
    }
    __syncthreads();
    float s = 0.f;
    #pragma unroll 8
    for (int o = 0; o < COUT; ++o) s += c2s[o*65 + o2] * wcol[ci*64 + o];
    w2b[(size_t)bp*4096 + o2*64 + c] = f2bf(s * fv);
}

// ---------------------------------------------------------------------------
// conv v2 (round-4-proven): 512 blocks = b(4) x by(16) x bx(8); tile = 8 rows
// x 16 px, ALL 27 output channels per block (B-tile staged ONCE, each ds_read
// feeds 2 MFMAs).  Division-free branch-free staging.
// ---------------------------------------------------------------------------
static __device__ __forceinline__ void conv_lds_body(
        int id, int tid, const float* __restrict__ inter,
        const unsigned short* __restrict__ wk2, const float* __restrict__ com_b,
        float* __restrict__ om, float* smemf) {
    unsigned short* til = (unsigned short*)smemf;   // [182][24] shorts (8736B)
    int b  = id >> 7;          // 0..3
    int t7 = id & 127;
    int by = t7 >> 3;          // 0..15
    int bx = t7 & 7;           // 0..7
    int x0 = bx*16, y0 = by*8;
    int lane = tid & 63, wv = tid >> 6;
    int nn = lane & 15, qq = lane >> 4;

    // zero the dummy px row (180) once; staging never overwrites it
    if (tid < 24) til[180*24 + tid] = 0;

    // staging coords fixed per thread: cl = tid&15, cc = tid>>4 (0..15)
    int scl = tid & 15, scc = tid >> 4;
    int sgx  = x0 + scc - 1;
    int sgxc = max(sgx, 0);                 // <= 126, always in-bounds
    float sfx = ((unsigned)sgx < WW) ? 1.f : 0.f;

    f32x4 acc[2][2];
    #pragma unroll
    for (int nt = 0; nt < 2; ++nt)
        #pragma unroll
        for (int mh = 0; mh < 2; ++mh)
            #pragma unroll
            for (int j = 0; j < 4; ++j) acc[nt][mh][j] = 0.f;

    for (int cg = 0; cg < 4; ++cg) {
        __syncthreads();                    // previous cg's reads done
        const float* I = inter + ((size_t)(b*CIN + cg*16))*HW;

        // main staging: rows r=0..9, cc=0..15 (2560 elems, 10/thread)
        {
            const float* colp = I + (size_t)scl*HW + sgxc;
            unsigned short* tp = til + scc*24 + scl;
            #pragma unroll
            for (int r = 0; r < 10; ++r) {
                int gy  = y0 + r - 1;
                int gyc = min(max(gy, 0), HH-1);
                float m = ((unsigned)gy < HH) ? sfx : 0.f;
                float v = colp[(size_t)gyc*WW] * m;
                tp[r*(18*24)] = f2bf(v);
            }
        }
        // tail staging: cc=16,17 (320 elems), i = r*32 + ccb*16 + cl
        #pragma unroll
        for (int k = 0; k < 2; ++k) {
            int i = k*256 + tid;
            if (i < 320) {
                int cl  = i & 15;
                int ccb = (i >> 4) & 1;         // cc = 16+ccb
                int r   = i >> 5;               // 0..9
                int gx  = x0 + 15 + ccb;
                int gy  = y0 + r - 1;
                int gxc = min(gx, WW-1);
                int gyc = min(max(gy, 0), HH-1);
                float m = (((unsigned)gy < HH) && ((unsigned)gx < WW)) ? 1.f : 0.f;
                float v = I[(size_t)cl*HW + gyc*WW + gxc] * m;
                til[(r*18 + 16 + ccb)*24 + cl] = f2bf(v);
            }
        }
        __syncthreads();

        #pragma unroll
        for (int ch = 0; ch < 5; ++ch) {
            short8 a0 = *(const short8*)(wk2 +
                (((size_t)(cg*5 + ch)*32 + nn)*32 + qq*8));
            short8 a1 = *(const short8*)(wk2 +
                (((size_t)(cg*5 + ch)*32 + 16 + nn)*32 + qq*8));
            int tap = ch*2 + (qq >> 1);
            #pragma unroll
            for (int nt = 0; nt < 2; ++nt) {
                int row = wv*2 + nt;            // 0..7
                int px_idx;
                if (tap > 8) px_idx = 180;
                else {
                    int ky = tap/3, kx = tap%3;
                    px_idx = (row + ky)*18 + (nn + kx);
                }
                short8 bfr = *(const short8*)(til + px_idx*24 + (qq&1)*8);
                acc[nt][0] = __builtin_amdgcn_mfma_f32_16x16x32_bf16(
                                 a0, bfr, acc[nt][0], 0, 0, 0);
                acc[nt][1] = __builtin_amdgcn_mfma_f32_16x16x32_bf16(
                                 a1, bfr, acc[nt][1], 0, 0, 0);
            }
        }
    }

    float* op = om + (size_t)b*27*HW;
    #pragma unroll
    for (int nt = 0; nt < 2; ++nt) {
        int pix = (y0 + wv*2 + nt)*WW + x0 + nn;
        #pragma unroll
        for (int mh = 0; mh < 2; ++mh)
            #pragma unroll
            for (int j = 0; j < 4; ++j) {
                int oc = mh*16 + qq*4 + j;
                if (oc < 27)
                    op[(size_t)oc*HW + pix] = acc[nt][mh][j] + com_b[oc];
            }
    }
}

// ---------------------------------------------------------------------------
// K2: conv (512) + w2 (576) + fT transpose (1024) = 2112 blocks
// ---------------------------------------------------------------------------
__global__ __launch_bounds__(256) void main2_kernel(
        const float* __restrict__ input_feat,
        const float* __restrict__ inter,
        const unsigned short* __restrict__ wk2,
        const float* __restrict__ com_b,
        const float* __restrict__ weight,
        const float* __restrict__ c2w,
        const float* __restrict__ c1w,
        const float* __restrict__ fea,
        float* __restrict__ om, unsigned short* __restrict__ w2b,
        unsigned short* __restrict__ fT) {
    __shared__ __align__(16) float smem[4416];
    int id = blockIdx.x, tid = threadIdx.x;
    if (id < 512)        conv_lds_body(id, tid, inter, wk2, com_b, om, smem);
    else if (id < 1088)  w2_body(id - 512, tid, weight, c2w, c1w, fea, w2b,
                                 smem, smem + 64*65);
    else                 transpose_body(input_feat, fT, id - 1088, tid, smem);
}

// ---------------------------------------------------------------------------
// K3: main DCN GEMM, bf16 MFMA, split-K across wave pairs.
// v5: BARRIER-FREE main loop (round-0 structure) + XCD batch-binding.
//  * Round-4's per-tap global_load_lds staging forced a vmcnt(0)+lgkmcnt(0)
//    drain + barrier every tap (9x rendezvous of 4 waves on the slowest
//    scattered gather) — ~15k cyc/tap vs ~3k of actual work.  Removed: A-frags
//    load directly from w2b (72KB/batch, L2-hot under binding; addr depends
//    only on nn -> 16 lines/mt, L1-served after first touch).
//  * XCD batch-binding kept (proven: FETCH 13.6 -> 8.1 MB): xcd = blk&7,
//    b = xcd>>1; per-XCD working set fits the 4MB L2.
//  * Waves free-run at 8/SIMD; only barrier is the split-K combine epilogue.
// ---------------------------------------------------------------------------
__global__ __launch_bounds__(256) void dcn_main_kernel(
        const unsigned short* __restrict__ fT,
        const unsigned short* __restrict__ w2b,
        const float* __restrict__ bias2,
        const float* __restrict__ om,
        float* __restrict__ out) {
    __shared__ float red[16*2*64];   // [idx16][strip][lane] = 8 KB
    int id = blockIdx.x;                 // 0..2047
    int xcd = id & 7;                    // round-robin XCD assignment
    int jj  = id >> 3;                   // 0..255 within this XCD
    int b   = xcd >> 1;                  // 2 XCDs per batch -> per-XCD L2 fit
    int y   = jj & 127;
    int xq  = ((xcd & 1) << 1) | (jj >> 7);   // 0..3 (bijective)

    int t = threadIdx.x;
    int lane = t & 63, wv = t >> 6;
    int strip = wv >> 1, kh = wv & 1;
    int nn = lane & 15, qq = lane >> 4;
    int px0 = xq*32 + strip*16;
    int x = px0 + nn;
    int pix = y*WW + x;
    const unsigned short* Fb = fT + (size_t)b*HW*64;
    const float* omb = om + (size_t)b*27*HW;
    const unsigned short* w2p = w2b + (size_t)(b*9)*4096 + kh*32 + qq*8;
    int co = kh*32 + qq*8;

    f32x4 acc[4];
    #pragma unroll
    for (int mt = 0; mt < 4; ++mt)
        #pragma unroll
        for (int j = 0; j < 4; ++j)
            acc[mt][j] = kh ? bias2[mt*16 + qq*4 + j] : 0.f;

    float omy = omb[pix];
    float omx = omb[(size_t)HW + pix];
    float omm = omb[(size_t)18*HW + pix];

    #pragma unroll
    for (int p = 0; p < 9; ++p) {
        // A-frags for my K-half (L2/L1-hot)
        short8 afr[4];
        #pragma unroll
        for (int mt = 0; mt < 4; ++mt)
            afr[mt] = *(const short8*)(w2p + (size_t)p*4096 + (mt*16 + nn)*64);

        // bilinear corner weights for my pixel
        float mv = 1.f / (1.f + expf(-omm));
        float ysv = (float)(y - 1 + p/3) + omy;
        float xsv = (float)(x - 1 + p%3) + omx;
        float y0f = floorf(ysv), x0f = floorf(xsv);
        float ly = ysv - y0f, lx = xsv - x0f;
        int y0 = (int)y0f, x0i = (int)x0f;
        int y1 = y0 + 1, x1 = x0i + 1;
        float vy0 = (y0 >= 0 && y0 < HH) ? 1.f : 0.f;
        float vy1 = (y1 >= 0 && y1 < HH) ? 1.f : 0.f;
        float vx0 = (x0i >= 0 && x0i < WW) ? 1.f : 0.f;
        float vx1 = (x1 >= 0 && x1 < WW) ? 1.f : 0.f;
        float w00 = (1.f-ly)*(1.f-lx)*mv * vy0*vx0;
        float w01 = (1.f-ly)*lx      *mv * vy0*vx1;
        float w10 = ly      *(1.f-lx)*mv * vy1*vx0;
        float w11 = ly      *lx      *mv * vy1*vx1;
        int y0c = min(max(y0,0),HH-1), y1c = min(max(y1,0),HH-1);
        int x0c = min(max(x0i,0),WW-1), x1c = min(max(x1,0),WW-1);
        int i00 = y0c*WW + x0c, i01 = y0c*WW + x1c;
        int i10 = y1c*WW + x0c, i11 = y1c*WW + x1c;

        // prefetch next p's om
        if (p < 8) {
            omy = omb[(size_t)(2*p+2)*HW + pix];
            omx = omb[(size_t)(2*p+3)*HW + pix];
            omm = omb[(size_t)(19+p )*HW + pix];
        }

        // gather my 8 channels' 4 corners (16B each, channel-contiguous)
        short8 c00 = *(const short8*)(Fb + (size_t)i00*64 + co);
        short8 c01 = *(const short8*)(Fb + (size_t)i01*64 + co);
        short8 c10 = *(const short8*)(Fb + (size_t)i10*64 + co);
        short8 c11 = *(const short8*)(Fb + (size_t)i11*64 + co);

        // pack
        unsigned int pw[4];
        #pragma unroll
        for (int jp = 0; jp < 4; ++jp) {
            float v0 = w00*bf2f((unsigned short)c00[2*jp])
                     + w01*bf2f((unsigned short)c01[2*jp])
                     + w10*bf2f((unsigned short)c10[2*jp])
                     + w11*bf2f((unsigned short)c11[2*jp]);
            float v1 = w00*bf2f((unsigned short)c00[2*jp+1])
                     + w01*bf2f((unsigned short)c01[2*jp+1])
                     + w10*bf2f((unsigned short)c10[2*jp+1])
                     + w11*bf2f((unsigned short)c11[2*jp+1]);
            pw[jp] = (unsigned int)f2bf(v0) | ((unsigned int)f2bf(v1) << 16);
        }
        uint4v u4 = {pw[0], pw[1], pw[2], pw[3]};
        short8 bfr = __builtin_bit_cast(short8, u4);

        // MFMA (my K-half only)
        #pragma unroll
        for (int mt = 0; mt < 4; ++mt)
            acc[mt] = __builtin_amdgcn_mfma_f32_16x16x32_bf16(
                          afr[mt], bfr, acc[mt], 0, 0, 0);
    }

    // combine wave-pair partials via LDS (conflict-free: lane is fastest dim)
    if (kh == 0) {
        #pragma unroll
        for (int mt = 0; mt < 4; ++mt)
            #pragma unroll
            for (int j = 0; j < 4; ++j)
                red[(mt*4 + j)*128 + strip*64 + lane] = acc[mt][j];
    }
    __syncthreads();
    if (kh == 1) {
        float* outp = out + (size_t)b*COUT*HW + (size_t)y*WW + px0 + nn;
        #pragma unroll
        for (int mt = 0; mt < 4; ++mt)
            #pragma unroll
            for (int j = 0; j < 4; ++j)
                outp[(size_t)(mt*16 + qq*4 + j)*HW] =
                    acc[mt][j] + red[(mt*4 + j)*128 + strip*64 + lane];
    }
}

// ---------------------------------------------------------------------------
extern "C" void kernel_launch(void* const* d_in, const int* in_sizes, int n_in,
                              void* d_out, int out_size, void* d_ws, size_t ws_size,
                              hipStream_t stream) {
    const float* input_feat = (const float*)d_in[0];
    const float* inter      = (const float*)d_in[1];
    const float* fea        = (const float*)d_in[2];
    const float* weight     = (const float*)d_in[3];
    const float* bias       = (const float*)d_in[4];
    const float* com_w      = (const float*)d_in[5];
    const float* com_b      = (const float*)d_in[6];
    const float* c1w        = (const float*)d_in[7];
    const float* c2w        = (const float*)d_in[8];
    float* out = (float*)d_out;

    float* ws    = (float*)d_ws;
    float* bias2 = ws + 256;                               // 64 (in pad area)
    unsigned short* w2b = (unsigned short*)(ws + 512);     // 147456 us
    float* om    = ws + 512 + 73728;                       // 1769472 f
    unsigned short* wk2 = (unsigned short*)(om + 1769472); // 20480 us
    unsigned short* fT  = wk2 + 20480;                     // 4194304 us

    prep_kernel<<<81, 256, 0, stream>>>(com_w, c2w, bias, wk2, bias2);
    main2_kernel<<<2112, 256, 0, stream>>>(input_feat, inter, wk2, com_b,
                                           weight, c2w, c1w, fea, om, w2b, fT);
    dcn_main_kernel<<<2048, 256, 0, stream>>>(fT, w2b, bias2, om, out);
}

// Round 6
// 161.917 us; speedup vs baseline: 1.0966x; 1.0966x over previous
//
#include <hip/hip_runtime.h>
#include <math.h>

// Problem constants
#define BB 4
#define CIN 64
#define COUT 64
#define HH 128
#define WW 128
#define HW (HH*WW)

typedef __attribute__((ext_vector_type(8))) short short8;   // 8 bf16 = 4 VGPRs
typedef __attribute__((ext_vector_type(4))) float f32x4;
typedef __attribute__((ext_vector_type(4))) unsigned int uint4v;

static __device__ __forceinline__ unsigned short f2bf(float f) {
    unsigned int u = __builtin_bit_cast(unsigned int, f);
    u += 0x7fffu + ((u >> 16) & 1u);          // round-to-nearest-even
    return (unsigned short)(u >> 16);
}
static __device__ __forceinline__ float bf2f(unsigned short h) {
    unsigned int u = ((unsigned int)h) << 16;
    return __builtin_bit_cast(float, u);
}

// ---------------------------------------------------------------------------
// K1: wkpack (80 blocks) + bias2 (1 block).  Tiny; everything else moved out.
// ---------------------------------------------------------------------------
__global__ __launch_bounds__(256) void prep_kernel(
        const float* __restrict__ com_w, const float* __restrict__ c2w,
        const float* __restrict__ bias,
        unsigned short* __restrict__ wk2, float* __restrict__ bias2) {
    int id = blockIdx.x, tid = threadIdx.x;
    if (id < 80) {
        int i = id*256 + tid;               // < 20480
        int k = i & 31, oc = (i >> 5) & 31;
        int cc5 = i >> 10;                  // cg*5 + chunk
        int cg = cc5 / 5, ch = cc5 % 5;
        int tap = ch*2 + (k >> 4);
        int c = cg*16 + (k & 15);
        float v = 0.f;
        if (tap < 9 && oc < 27) v = com_w[((size_t)oc*64 + c)*9 + tap];
        wk2[i] = f2bf(v);
    } else if (tid < COUT) {
        float s2 = 0.f;
        for (int o = 0; o < COUT; ++o) s2 += c2w[tid*COUT + o] * bias[o];
        bias2[tid] = s2;
    }
}

// ---------------------------------------------------------------------------
// channel-last bf16 transpose of one (b, 64-px strip): src[b][c][px]->dst[b][px][c]
// ---------------------------------------------------------------------------
static __device__ __forceinline__ void transpose_body(
        const float* __restrict__ srcb, unsigned short* __restrict__ dstb,
        int tb, int tid, float* lt /* 64*65 floats */) {
    int b = tb >> 8;
    int px0 = (tb & 255) * 64;
    const float* src = srcb + (size_t)b*CIN*HW + px0;
    for (int i = tid; i < 4096; i += 256) {
        int c = i >> 6, px = i & 63;
        lt[c*65 + px] = src[(size_t)c*HW + px];
    }
    __syncthreads();
    int q = tid & 3, px = tid >> 2;
    unsigned short* dst = dstb + ((size_t)b*HW + px0 + px)*64 + q*16;
    #pragma unroll
    for (int s = 0; s < 2; ++s) {
        short8 pk;
        #pragma unroll
        for (int j = 0; j < 8; ++j)
            pk[j] = (short)f2bf(lt[(q*16 + s*8 + j)*65 + px]);
        *(short8*)(dst + s*8) = pk;
    }
}

// ---------------------------------------------------------------------------
// w2 with INLINE fvec (wave-reduced): W2b[b][p][o2][c] bf16 (MFMA A layout)
// Unswizzled: dcn reads A-frags directly from global (L1/L2-hot).
// ---------------------------------------------------------------------------
static __device__ __forceinline__ void w2_body(
        int wid, int tid, const float* __restrict__ weight,
        const float* __restrict__ c2w, const float* __restrict__ c1w,
        const float* __restrict__ fea,
        unsigned short* __restrict__ w2b, float* c2s, float* wcol) {
    int o2 = tid & 63, ci = tid >> 6;
    int lane = tid & 63;
    int bp = wid >> 4;
    int c_base = (wid & 15)*4;
    int p = bp % 9, b = bp / 9;
    int c = c_base + ci;

    // inline fvec[b][c] for this wave's c: 4 MAC/lane + wave reduce
    float part = 0.f;
    #pragma unroll
    for (int s = 0; s < 4; ++s)
        part += c1w[c*(4*CIN) + lane + s*64] * fea[b*(4*CIN) + lane + s*64];
    #pragma unroll
    for (int off = 32; off; off >>= 1) part += __shfl_down(part, off);
    float fv = __shfl(part, 0);

    for (int idx = tid; idx < 4096; idx += 256) {
        int o2r = idx >> 6, oc = idx & 63;
        c2s[oc*65 + o2r] = c2w[idx];
    }
    {
        int o = tid & 63, cw = tid >> 6;
        wcol[cw*64 + o] = weight[(o*CIN + (c_base + cw))*9 + p];
    }
    __syncthreads();
    float s = 0.f;
    #pragma unroll 8
    for (int o = 0; o < COUT; ++o) s += c2s[o*65 + o2] * wcol[ci*64 + o];
    w2b[(size_t)bp*4096 + o2*64 + c] = f2bf(s * fv);
}

// ---------------------------------------------------------------------------
// conv v2 (round-4-proven): 512 blocks = b(4) x by(16) x bx(8); tile = 8 rows
// x 16 px, ALL 27 output channels per block (B-tile staged ONCE, each ds_read
// feeds 2 MFMAs).  Division-free branch-free staging.
// ---------------------------------------------------------------------------
static __device__ __forceinline__ void conv_lds_body(
        int id, int tid, const float* __restrict__ inter,
        const unsigned short* __restrict__ wk2, const float* __restrict__ com_b,
        float* __restrict__ om, float* smemf) {
    unsigned short* til = (unsigned short*)smemf;   // [182][24] shorts (8736B)
    int b  = id >> 7;          // 0..3
    int t7 = id & 127;
    int by = t7 >> 3;          // 0..15
    int bx = t7 & 7;           // 0..7
    int x0 = bx*16, y0 = by*8;
    int lane = tid & 63, wv = tid >> 6;
    int nn = lane & 15, qq = lane >> 4;

    // zero the dummy px row (180) once; staging never overwrites it
    if (tid < 24) til[180*24 + tid] = 0;

    // staging coords fixed per thread: cl = tid&15, cc = tid>>4 (0..15)
    int scl = tid & 15, scc = tid >> 4;
    int sgx  = x0 + scc - 1;
    int sgxc = max(sgx, 0);                 // <= 126, always in-bounds
    float sfx = ((unsigned)sgx < WW) ? 1.f : 0.f;

    f32x4 acc[2][2];
    #pragma unroll
    for (int nt = 0; nt < 2; ++nt)
        #pragma unroll
        for (int mh = 0; mh < 2; ++mh)
            #pragma unroll
            for (int j = 0; j < 4; ++j) acc[nt][mh][j] = 0.f;

    for (int cg = 0; cg < 4; ++cg) {
        __syncthreads();                    // previous cg's reads done
        const float* I = inter + ((size_t)(b*CIN + cg*16))*HW;

        // main staging: rows r=0..9, cc=0..15 (2560 elems, 10/thread)
        {
            const float* colp = I + (size_t)scl*HW + sgxc;
            unsigned short* tp = til + scc*24 + scl;
            #pragma unroll
            for (int r = 0; r < 10; ++r) {
                int gy  = y0 + r - 1;
                int gyc = min(max(gy, 0), HH-1);
                float m = ((unsigned)gy < HH) ? sfx : 0.f;
                float v = colp[(size_t)gyc*WW] * m;
                tp[r*(18*24)] = f2bf(v);
            }
        }
        // tail staging: cc=16,17 (320 elems), i = r*32 + ccb*16 + cl
        #pragma unroll
        for (int k = 0; k < 2; ++k) {
            int i = k*256 + tid;
            if (i < 320) {
                int cl  = i & 15;
                int ccb = (i >> 4) & 1;         // cc = 16+ccb
                int r   = i >> 5;               // 0..9
                int gx  = x0 + 15 + ccb;
                int gy  = y0 + r - 1;
                int gxc = min(gx, WW-1);
                int gyc = min(max(gy, 0), HH-1);
                float m = (((unsigned)gy < HH) && ((unsigned)gx < WW)) ? 1.f : 0.f;
                float v = I[(size_t)cl*HW + gyc*WW + gxc] * m;
                til[(r*18 + 16 + ccb)*24 + cl] = f2bf(v);
            }
        }
        __syncthreads();

        #pragma unroll
        for (int ch = 0; ch < 5; ++ch) {
            short8 a0 = *(const short8*)(wk2 +
                (((size_t)(cg*5 + ch)*32 + nn)*32 + qq*8));
            short8 a1 = *(const short8*)(wk2 +
                (((size_t)(cg*5 + ch)*32 + 16 + nn)*32 + qq*8));
            int tap = ch*2 + (qq >> 1);
            #pragma unroll
            for (int nt = 0; nt < 2; ++nt) {
                int row = wv*2 + nt;            // 0..7
                int px_idx;
                if (tap > 8) px_idx = 180;
                else {
                    int ky = tap/3, kx = tap%3;
                    px_idx = (row + ky)*18 + (nn + kx);
                }
                short8 bfr = *(const short8*)(til + px_idx*24 + (qq&1)*8);
                acc[nt][0] = __builtin_amdgcn_mfma_f32_16x16x32_bf16(
                                 a0, bfr, acc[nt][0], 0, 0, 0);
                acc[nt][1] = __builtin_amdgcn_mfma_f32_16x16x32_bf16(
                                 a1, bfr, acc[nt][1], 0, 0, 0);
            }
        }
    }

    float* op = om + (size_t)b*27*HW;
    #pragma unroll
    for (int nt = 0; nt < 2; ++nt) {
        int pix = (y0 + wv*2 + nt)*WW + x0 + nn;
        #pragma unroll
        for (int mh = 0; mh < 2; ++mh)
            #pragma unroll
            for (int j = 0; j < 4; ++j) {
                int oc = mh*16 + qq*4 + j;
                if (oc < 27)
                    op[(size_t)oc*HW + pix] = acc[nt][mh][j] + com_b[oc];
            }
    }
}

// ---------------------------------------------------------------------------
// K2: conv (512) + w2 (576) + fT transpose (1024) = 2112 blocks
// ---------------------------------------------------------------------------
__global__ __launch_bounds__(256) void main2_kernel(
        const float* __restrict__ input_feat,
        const float* __restrict__ inter,
        const unsigned short* __restrict__ wk2,
        const float* __restrict__ com_b,
        const float* __restrict__ weight,
        const float* __restrict__ c2w,
        const float* __restrict__ c1w,
        const float* __restrict__ fea,
        float* __restrict__ om, unsigned short* __restrict__ w2b,
        unsigned short* __restrict__ fT) {
    __shared__ __align__(16) float smem[4416];
    int id = blockIdx.x, tid = threadIdx.x;
    if (id < 512)        conv_lds_body(id, tid, inter, wk2, com_b, om, smem);
    else if (id < 1088)  w2_body(id - 512, tid, weight, c2w, c1w, fea, w2b,
                                 smem, smem + 64*65);
    else                 transpose_body(input_feat, fT, id - 1088, tid, smem);
}

// ---------------------------------------------------------------------------
// K3: main DCN GEMM, bf16 MFMA, split-K across wave pairs.
// v6: LDS-STAGED GATHER TILE.  R4 vs R5 showed the cost is the scattered
// 128B-line fT gathers (R4's lockstep only masked it via kh-pair L1 hits).
// Offsets are small (om ~ N(0,0.24)), so a block's bilinear corners nearly
// always land in a 6-row x 36-px window around its tile:
//  * stage that window (27.6 KB) into LDS once per block, coalesced,
//    XOR-swizzled (byte ^= (pix&7)<<4) -> ~2-way banks on gather reads;
//  * gathers become ds_reads; per-lane GLOBAL FALLBACK branch for the rare
//    out-of-window corner (bit-identical bytes either way);
//  * main loop barrier-free (no lockstep needed); A-frags direct from global
//    (4KB/tap, L1-hot for all waves regardless of drift);
//  * reduction buffer aliases the tile after a post-loop barrier.
// LDS 27.6KB -> 5 blocks/CU.  XCD batch-binding kept (FETCH 13.6->8.1 MB).
// ---------------------------------------------------------------------------
__global__ __launch_bounds__(256) void dcn_main_kernel(
        const unsigned short* __restrict__ fT,
        const unsigned short* __restrict__ w2b,
        const float* __restrict__ bias2,
        const float* __restrict__ om,
        float* __restrict__ out) {
    __shared__ __align__(16) unsigned short gtile[6*36*64];   // 27648 B
    int id = blockIdx.x;                 // 0..2047
    int xcd = id & 7;                    // round-robin XCD assignment
    int jj  = id >> 3;                   // 0..255 within this XCD
    int b   = xcd >> 1;                  // 2 XCDs per batch -> per-XCD L2 fit
    int y   = jj & 127;
    int xq  = ((xcd & 1) << 1) | (jj >> 7);   // 0..3 (bijective)

    int t = threadIdx.x;
    int lane = t & 63, wv = t >> 6;
    int strip = wv >> 1, kh = wv & 1;
    int nn = lane & 15, qq = lane >> 4;
    int px0 = xq*32 + strip*16;
    int x = px0 + nn;
    int pix = y*WW + x;
    const unsigned short* Fb = fT + (size_t)b*HW*64;
    const float* omb = om + (size_t)b*27*HW;
    const unsigned short* w2p = w2b + (size_t)(b*9)*4096 + kh*32 + qq*8;
    int co  = kh*32 + qq*8;       // element offset in a 64-ch pixel row
    int cob = kh*64 + qq*16;      // byte offset within a 128B pixel row

    // gather-tile window (always fully inside the image)
    int ybase = min(max(y - 2, 0), HH - 6);        // [0,122]
    int xbase = min(max(xq*32 - 2, 0), WW - 36);   // [0,92]

    // stage 6x36 pixel rows = 1728 16B chunks, coalesced, swizzled
    char* gt = (char*)gtile;
    #pragma unroll
    for (int it = 0; it < 7; ++it) {
        int c = it*256 + t;
        if (c < 1728) {
            int pl = c >> 3;                    // local pixel 0..215
            int ci = c & 7;                     // 16B chunk in pixel
            int sy = (pl*1821) >> 16;           // pl/36 (exact for pl<216)
            int sx = pl - sy*36;
            short8 v = *(const short8*)(Fb +
                ((size_t)(ybase + sy)*WW + xbase + sx)*64 + ci*8);
            int bo = (pl*128 + ci*16) ^ ((pl & 7) << 4);
            *(short8*)(gt + bo) = v;
        }
    }

    f32x4 acc[4];
    #pragma unroll
    for (int mt = 0; mt < 4; ++mt)
        #pragma unroll
        for (int j = 0; j < 4; ++j)
            acc[mt][j] = kh ? bias2[mt*16 + qq*4 + j] : 0.f;

    float omy = omb[pix];
    float omx = omb[(size_t)HW + pix];
    float omm = omb[(size_t)18*HW + pix];
    __syncthreads();                             // tile ready

    #pragma unroll
    for (int p = 0; p < 9; ++p) {
        // A-frags for my K-half (tiny, L1/L2-hot)
        short8 afr[4];
        #pragma unroll
        for (int mt = 0; mt < 4; ++mt)
            afr[mt] = *(const short8*)(w2p + (size_t)p*4096 + (mt*16 + nn)*64);

        // bilinear corner weights for my pixel
        float mv = 1.f / (1.f + expf(-omm));
        float ysv = (float)(y - 1 + p/3) + omy;
        float xsv = (float)(x - 1 + p%3) + omx;
        float y0f = floorf(ysv), x0f = floorf(xsv);
        float ly = ysv - y0f, lx = xsv - x0f;
        int y0 = (int)y0f, x0i = (int)x0f;
        int y1 = y0 + 1, x1 = x0i + 1;
        float vy0 = (y0 >= 0 && y0 < HH) ? 1.f : 0.f;
        float vy1 = (y1 >= 0 && y1 < HH) ? 1.f : 0.f;
        float vx0 = (x0i >= 0 && x0i < WW) ? 1.f : 0.f;
        float vx1 = (x1 >= 0 && x1 < WW) ? 1.f : 0.f;
        float w00 = (1.f-ly)*(1.f-lx)*mv * vy0*vx0;
        float w01 = (1.f-ly)*lx      *mv * vy0*vx1;
        float w10 = ly      *(1.f-lx)*mv * vy1*vx0;
        float w11 = ly      *lx      *mv * vy1*vx1;
        int y0c = min(max(y0,0),HH-1), y1c = min(max(y1,0),HH-1);
        int x0c = min(max(x0i,0),WW-1), x1c = min(max(x1,0),WW-1);

        // prefetch next p's om
        if (p < 8) {
            omy = omb[(size_t)(2*p+2)*HW + pix];
            omx = omb[(size_t)(2*p+3)*HW + pix];
            omm = omb[(size_t)(19+p )*HW + pix];
        }

        // gather 4 corners: LDS fast path, global fallback (rare)
        short8 c00, c01, c10, c11;
        {
            int sy0 = y0c - ybase, sy1 = y1c - ybase;
            int sx0 = x0c - xbase, sx1 = x1c - xbase;
            bool allin = ((unsigned)sy0 < 6) & ((unsigned)sy1 < 6) &
                         ((unsigned)sx0 < 36) & ((unsigned)sx1 < 36);
            if (allin) {
                int p00 = sy0*36 + sx0, p01 = sy0*36 + sx1;
                int p10 = sy1*36 + sx0, p11 = sy1*36 + sx1;
                c00 = *(const short8*)(gt + ((p00*128 + cob) ^ ((p00&7)<<4)));
                c01 = *(const short8*)(gt + ((p01*128 + cob) ^ ((p01&7)<<4)));
                c10 = *(const short8*)(gt + ((p10*128 + cob) ^ ((p10&7)<<4)));
                c11 = *(const short8*)(gt + ((p11*128 + cob) ^ ((p11&7)<<4)));
            } else {
                int i00 = y0c*WW + x0c, i01 = y0c*WW + x1c;
                int i10 = y1c*WW + x0c, i11 = y1c*WW + x1c;
                c00 = *(const short8*)(Fb + (size_t)i00*64 + co);
                c01 = *(const short8*)(Fb + (size_t)i01*64 + co);
                c10 = *(const short8*)(Fb + (size_t)i10*64 + co);
                c11 = *(const short8*)(Fb + (size_t)i11*64 + co);
            }
        }

        // pack
        unsigned int pw[4];
        #pragma unroll
        for (int jp = 0; jp < 4; ++jp) {
            float v0 = w00*bf2f((unsigned short)c00[2*jp])
                     + w01*bf2f((unsigned short)c01[2*jp])
                     + w10*bf2f((unsigned short)c10[2*jp])
                     + w11*bf2f((unsigned short)c11[2*jp]);
            float v1 = w00*bf2f((unsigned short)c00[2*jp+1])
                     + w01*bf2f((unsigned short)c01[2*jp+1])
                     + w10*bf2f((unsigned short)c10[2*jp+1])
                     + w11*bf2f((unsigned short)c11[2*jp+1]);
            pw[jp] = (unsigned int)f2bf(v0) | ((unsigned int)f2bf(v1) << 16);
        }
        uint4v u4 = {pw[0], pw[1], pw[2], pw[3]};
        short8 bfr = __builtin_bit_cast(short8, u4);

        // MFMA (my K-half only)
        #pragma unroll
        for (int mt = 0; mt < 4; ++mt)
            acc[mt] = __builtin_amdgcn_mfma_f32_16x16x32_bf16(
                          afr[mt], bfr, acc[mt], 0, 0, 0);
    }

    // combine wave-pair partials; reduction buffer ALIASES gtile, so first
    // ensure all waves finished their LDS gathers.
    __syncthreads();
    float* red = (float*)gtile;
    if (kh == 0) {
        #pragma unroll
        for (int mt = 0; mt < 4; ++mt)
            #pragma unroll
            for (int j = 0; j < 4; ++j)
                red[(mt*4 + j)*128 + strip*64 + lane] = acc[mt][j];
    }
    __syncthreads();
    if (kh == 1) {
        float* outp = out + (size_t)b*COUT*HW + (size_t)y*WW + px0 + nn;
        #pragma unroll
        for (int mt = 0; mt < 4; ++mt)
            #pragma unroll
            for (int j = 0; j < 4; ++j)
                outp[(size_t)(mt*16 + qq*4 + j)*HW] =
                    acc[mt][j] + red[(mt*4 + j)*128 + strip*64 + lane];
    }
}

// ---------------------------------------------------------------------------
extern "C" void kernel_launch(void* const* d_in, const int* in_sizes, int n_in,
                              void* d_out, int out_size, void* d_ws, size_t ws_size,
                              hipStream_t stream) {
    const float* input_feat = (const float*)d_in[0];
    const float* inter      = (const float*)d_in[1];
    const float* fea        = (const float*)d_in[2];
    const float* weight     = (const float*)d_in[3];
    const float* bias       = (const float*)d_in[4];
    const float* com_w      = (const float*)d_in[5];
    const float* com_b      = (const float*)d_in[6];
    const float* c1w        = (const float*)d_in[7];
    const float* c2w        = (const float*)d_in[8];
    float* out = (float*)d_out;

    float* ws    = (float*)d_ws;
    float* bias2 = ws + 256;                               // 64 (in pad area)
    unsigned short* w2b = (unsigned short*)(ws + 512);     // 147456 us
    float* om    = ws + 512 + 73728;                       // 1769472 f
    unsigned short* wk2 = (unsigned short*)(om + 1769472); // 20480 us
    unsigned short* fT  = wk2 + 20480;                     // 4194304 us

    prep_kernel<<<81, 256, 0, stream>>>(com_w, c2w, bias, wk2, bias2);
    main2_kernel<<<2112, 256, 0, stream>>>(input_feat, inter, wk2, com_b,
                                           weight, c2w, c1w, fea, om, w2b, fT);
    dcn_main_kernel<<<2048, 256, 0, stream>>>(fT, w2b, bias2, om, out);
}

// Round 8
// 161.076 us; speedup vs baseline: 1.1023x; 1.0052x over previous
//
#include <hip/hip_runtime.h>
#include <math.h>

// Problem constants
#define BB 4
#define CIN 64
#define COUT 64
#define HH 128
#define WW 128
#define HW (HH*WW)

typedef __attribute__((ext_vector_type(8))) short short8;   // 8 bf16 = 4 VGPRs
typedef __attribute__((ext_vector_type(4))) float f32x4;
typedef __attribute__((ext_vector_type(2))) float f32x2;
typedef __attribute__((ext_vector_type(4))) unsigned int uint4v;

static __device__ __forceinline__ unsigned short f2bf(float f) {
    unsigned int u = __builtin_bit_cast(unsigned int, f);
    u += 0x7fffu + ((u >> 16) & 1u);          // round-to-nearest-even
    return (unsigned short)(u >> 16);
}
static __device__ __forceinline__ float bf2f(unsigned short h) {
    unsigned int u = ((unsigned int)h) << 16;
    return __builtin_bit_cast(float, u);
}
// pack 2 f32 -> 2 bf16 in one HW instruction (RNE, == f2bf on finite vals)
static __device__ __forceinline__ unsigned int cvtpk_bf16(float lo, float hi) {
    unsigned int r;
    asm("v_cvt_pk_bf16_f32 %0, %1, %2" : "=v"(r) : "v"(lo), "v"(hi));
    return r;
}
// unpack 2 bf16 from a u32 into float2 (2 inst)
static __device__ __forceinline__ f32x2 bfpair(unsigned int u) {
    f32x2 r;
    r[0] = __builtin_bit_cast(float, u << 16);
    r[1] = __builtin_bit_cast(float, u & 0xffff0000u);
    return r;
}

// ---------------------------------------------------------------------------
// K1: wkpack (80 blocks) + bias2 (1 block).  Tiny; everything else moved out.
// ---------------------------------------------------------------------------
__global__ __launch_bounds__(256) void prep_kernel(
        const float* __restrict__ com_w, const float* __restrict__ c2w,
        const float* __restrict__ bias,
        unsigned short* __restrict__ wk2, float* __restrict__ bias2) {
    int id = blockIdx.x, tid = threadIdx.x;
    if (id < 80) {
        int i = id*256 + tid;               // < 20480
        int k = i & 31, oc = (i >> 5) & 31;
        int cc5 = i >> 10;                  // cg*5 + chunk
        int cg = cc5 / 5, ch = cc5 % 5;
        int tap = ch*2 + (k >> 4);
        int c = cg*16 + (k & 15);
        float v = 0.f;
        if (tap < 9 && oc < 27) v = com_w[((size_t)oc*64 + c)*9 + tap];
        wk2[i] = f2bf(v);
    } else if (tid < COUT) {
        float s2 = 0.f;
        for (int o = 0; o < COUT; ++o) s2 += c2w[tid*COUT + o] * bias[o];
        bias2[tid] = s2;
    }
}

// ---------------------------------------------------------------------------
// channel-last bf16 transpose of one (b, 64-px strip): src[b][c][px]->dst[b][px][c]
// ---------------------------------------------------------------------------
static __device__ __forceinline__ void transpose_body(
        const float* __restrict__ srcb, unsigned short* __restrict__ dstb,
        int tb, int tid, float* lt /* 64*65 floats */) {
    int b = tb >> 8;
    int px0 = (tb & 255) * 64;
    const float* src = srcb + (size_t)b*CIN*HW + px0;
    for (int i = tid; i < 4096; i += 256) {
        int c = i >> 6, px = i & 63;
        lt[c*65 + px] = src[(size_t)c*HW + px];
    }
    __syncthreads();
    int q = tid & 3, px = tid >> 2;
    unsigned short* dst = dstb + ((size_t)b*HW + px0 + px)*64 + q*16;
    #pragma unroll
    for (int s = 0; s < 2; ++s) {
        short8 pk;
        #pragma unroll
        for (int j = 0; j < 8; ++j)
            pk[j] = (short)f2bf(lt[(q*16 + s*8 + j)*65 + px]);
        *(short8*)(dst + s*8) = pk;
    }
}

// ---------------------------------------------------------------------------
// w2 with INLINE fvec (wave-reduced): W2b[b][p][o2][c] bf16 (MFMA A layout)
// Unswizzled: dcn reads A-frags directly from global (L1/L2-hot).
// ---------------------------------------------------------------------------
static __device__ __forceinline__ void w2_body(
        int wid, int tid, const float* __restrict__ weight,
        const float* __restrict__ c2w, const float* __restrict__ c1w,
        const float* __restrict__ fea,
        unsigned short* __restrict__ w2b, float* c2s, float* wcol) {
    int o2 = tid & 63, ci = tid >> 6;
    int lane = tid & 63;
    int bp = wid >> 4;
    int c_base = (wid & 15)*4;
    int p = bp % 9, b = bp / 9;
    int c = c_base + ci;

    // inline fvec[b][c] for this wave's c: 4 MAC/lane + wave reduce
    float part = 0.f;
    #pragma unroll
    for (int s = 0; s < 4; ++s)
        part += c1w[c*(4*CIN) + lane + s*64] * fea[b*(4*CIN) + lane + s*64];
    #pragma unroll
    for (int off = 32; off; off >>= 1) part += __shfl_down(part, off);
    float fv = __shfl(part, 0);

    for (int idx = tid; idx < 4096; idx += 256) {
        int o2r = idx >> 6, oc = idx & 63;
        c2s[oc*65 + o2r] = c2w[idx];
    }
    {
        int o = tid & 63, cw = tid >> 6;
        wcol[cw*64 + o] = weight[(o*CIN + (c_base + cw))*9 + p];
    }
    __syncthreads();
    float s = 0.f;
    #pragma unroll 8
    for (int o = 0; o < COUT; ++o) s += c2s[o*65 + o2] * wcol[ci*64 + o];
    w2b[(size_t)bp*4096 + o2*64 + c] = f2bf(s * fv);
}

// ---------------------------------------------------------------------------
// conv v2 (round-4-proven): 512 blocks = b(4) x by(16) x bx(8); tile = 8 rows
// x 16 px, ALL 27 output channels per block (B-tile staged ONCE, each ds_read
// feeds 2 MFMAs).  Division-free branch-free staging.
// ---------------------------------------------------------------------------
static __device__ __forceinline__ void conv_lds_body(
        int id, int tid, const float* __restrict__ inter,
        const unsigned short* __restrict__ wk2, const float* __restrict__ com_b,
        float* __restrict__ om, float* smemf) {
    unsigned short* til = (unsigned short*)smemf;   // [182][24] shorts (8736B)
    int b  = id >> 7;          // 0..3
    int t7 = id & 127;
    int by = t7 >> 3;          // 0..15
    int bx = t7 & 7;           // 0..7
    int x0 = bx*16, y0 = by*8;
    int lane = tid & 63, wv = tid >> 6;
    int nn = lane & 15, qq = lane >> 4;

    // zero the dummy px row (180) once; staging never overwrites it
    if (tid < 24) til[180*24 + tid] = 0;

    // staging coords fixed per thread: cl = tid&15, cc = tid>>4 (0..15)
    int scl = tid & 15, scc = tid >> 4;
    int sgx  = x0 + scc - 1;
    int sgxc = max(sgx, 0);                 // <= 126, always in-bounds
    float sfx = ((unsigned)sgx < WW) ? 1.f : 0.f;

    f32x4 acc[2][2];
    #pragma unroll
    for (int nt = 0; nt < 2; ++nt)
        #pragma unroll
        for (int mh = 0; mh < 2; ++mh)
            #pragma unroll
            for (int j = 0; j < 4; ++j) acc[nt][mh][j] = 0.f;

    for (int cg = 0; cg < 4; ++cg) {
        __syncthreads();                    // previous cg's reads done
        const float* I = inter + ((size_t)(b*CIN + cg*16))*HW;

        // main staging: rows r=0..9, cc=0..15 (2560 elems, 10/thread)
        {
            const float* colp = I + (size_t)scl*HW + sgxc;
            unsigned short* tp = til + scc*24 + scl;
            #pragma unroll
            for (int r = 0; r < 10; ++r) {
                int gy  = y0 + r - 1;
                int gyc = min(max(gy, 0), HH-1);
                float m = ((unsigned)gy < HH) ? sfx : 0.f;
                float v = colp[(size_t)gyc*WW] * m;
                tp[r*(18*24)] = f2bf(v);
            }
        }
        // tail staging: cc=16,17 (320 elems), i = r*32 + ccb*16 + cl
        #pragma unroll
        for (int k = 0; k < 2; ++k) {
            int i = k*256 + tid;
            if (i < 320) {
                int cl  = i & 15;
                int ccb = (i >> 4) & 1;         // cc = 16+ccb
                int r   = i >> 5;               // 0..9
                int gx  = x0 + 15 + ccb;
                int gy  = y0 + r - 1;
                int gxc = min(gx, WW-1);
                int gyc = min(max(gy, 0), HH-1);
                float m = (((unsigned)gy < HH) && ((unsigned)gx < WW)) ? 1.f : 0.f;
                float v = I[(size_t)cl*HW + gyc*WW + gxc] * m;
                til[(r*18 + 16 + ccb)*24 + cl] = f2bf(v);
            }
        }
        __syncthreads();

        #pragma unroll
        for (int ch = 0; ch < 5; ++ch) {
            short8 a0 = *(const short8*)(wk2 +
                (((size_t)(cg*5 + ch)*32 + nn)*32 + qq*8));
            short8 a1 = *(const short8*)(wk2 +
                (((size_t)(cg*5 + ch)*32 + 16 + nn)*32 + qq*8));
            int tap = ch*2 + (qq >> 1);
            #pragma unroll
            for (int nt = 0; nt < 2; ++nt) {
                int row = wv*2 + nt;            // 0..7
                int px_idx;
                if (tap > 8) px_idx = 180;
                else {
                    int ky = tap/3, kx = tap%3;
                    px_idx = (row + ky)*18 + (nn + kx);
                }
                short8 bfr = *(const short8*)(til + px_idx*24 + (qq&1)*8);
                acc[nt][0] = __builtin_amdgcn_mfma_f32_16x16x32_bf16(
                                 a0, bfr, acc[nt][0], 0, 0, 0);
                acc[nt][1] = __builtin_amdgcn_mfma_f32_16x16x32_bf16(
                                 a1, bfr, acc[nt][1], 0, 0, 0);
            }
        }
    }

    float* op = om + (size_t)b*27*HW;
    #pragma unroll
    for (int nt = 0; nt < 2; ++nt) {
        int pix = (y0 + wv*2 + nt)*WW + x0 + nn;
        #pragma unroll
        for (int mh = 0; mh < 2; ++mh)
            #pragma unroll
            for (int j = 0; j < 4; ++j) {
                int oc = mh*16 + qq*4 + j;
                if (oc < 27)
                    op[(size_t)oc*HW + pix] = acc[nt][mh][j] + com_b[oc];
            }
    }
}

// ---------------------------------------------------------------------------
// K2: conv (512) + w2 (576) + fT transpose (1024) = 2112 blocks
// ---------------------------------------------------------------------------
__global__ __launch_bounds__(256) void main2_kernel(
        const float* __restrict__ input_feat,
        const float* __restrict__ inter,
        const unsigned short* __restrict__ wk2,
        const float* __restrict__ com_b,
        const float* __restrict__ weight,
        const float* __restrict__ c2w,
        const float* __restrict__ c1w,
        const float* __restrict__ fea,
        float* __restrict__ om, unsigned short* __restrict__ w2b,
        unsigned short* __restrict__ fT) {
    __shared__ __align__(16) float smem[4416];
    int id = blockIdx.x, tid = threadIdx.x;
    if (id < 512)        conv_lds_body(id, tid, inter, wk2, com_b, om, smem);
    else if (id < 1088)  w2_body(id - 512, tid, weight, c2w, c1w, fea, w2b,
                                 smem, smem + 64*65);
    else                 transpose_body(input_feat, fT, id - 1088, tid, smem);
}

// ---------------------------------------------------------------------------
// K3: main DCN GEMM, bf16 MFMA, split-K across wave pairs.
// v7b (instruction-count theory; v7 resubmit after infra failure, with the
// __bf16 cast replaced by inline-asm v_cvt_pk_bf16_f32 — pure ISA path):
//  * pack vectorized: float2 weighted sum (v_pk_fma_f32, 32->16 FMA issues)
//    + one v_cvt_pk_bf16_f32 per bf16-pair (RNE == manual f2bf).
//  * 5-row gather window [y-2,y+2] (row y+3 needs dy>=1, 4.2-sigma -> global
//    fallback, bit-identical): LDS 27648 -> 23040 B -> 7 blocks/CU.
// Everything else identical to R6 (XCD batch-binding, swizzled LDS tile,
// barrier-free loop, A-frags direct from global).
// ---------------------------------------------------------------------------
__global__ __launch_bounds__(256) void dcn_main_kernel(
        const unsigned short* __restrict__ fT,
        const unsigned short* __restrict__ w2b,
        const float* __restrict__ bias2,
        const float* __restrict__ om,
        float* __restrict__ out) {
    __shared__ __align__(16) unsigned short gtile[5*36*64];   // 23040 B
    int id = blockIdx.x;                 // 0..2047
    int xcd = id & 7;                    // round-robin XCD assignment
    int jj  = id >> 3;                   // 0..255 within this XCD
    int b   = xcd >> 1;                  // 2 XCDs per batch -> per-XCD L2 fit
    int y   = jj & 127;
    int xq  = ((xcd & 1) << 1) | (jj >> 7);   // 0..3 (bijective)

    int t = threadIdx.x;
    int lane = t & 63, wv = t >> 6;
    int strip = wv >> 1, kh = wv & 1;
    int nn = lane & 15, qq = lane >> 4;
    int px0 = xq*32 + strip*16;
    int x = px0 + nn;
    int pix = y*WW + x;
    const unsigned short* Fb = fT + (size_t)b*HW*64;
    const float* omb = om + (size_t)b*27*HW;
    const unsigned short* w2p = w2b + (size_t)(b*9)*4096 + kh*32 + qq*8;
    int co  = kh*32 + qq*8;       // element offset in a 64-ch pixel row
    int cob = kh*64 + qq*16;      // byte offset within a 128B pixel row

    // gather-tile window (always fully inside the image): rows [ybase,ybase+4]
    int ybase = min(max(y - 2, 0), HH - 5);        // [0,123]
    int xbase = min(max(xq*32 - 2, 0), WW - 36);   // [0,92]

    // stage 5x36 pixel rows = 1440 16B chunks, coalesced, swizzled
    char* gt = (char*)gtile;
    #pragma unroll
    for (int it = 0; it < 6; ++it) {
        int c = it*256 + t;
        if (c < 1440) {
            int pl = c >> 3;                    // local pixel 0..179
            int ci = c & 7;                     // 16B chunk in pixel
            int sy = (pl*1821) >> 16;           // pl/36 (exact for pl<216)
            int sx = pl - sy*36;
            short8 v = *(const short8*)(Fb +
                ((size_t)(ybase + sy)*WW + xbase + sx)*64 + ci*8);
            int bo = (pl*128 + ci*16) ^ ((pl & 7) << 4);
            *(short8*)(gt + bo) = v;
        }
    }

    f32x4 acc[4];
    #pragma unroll
    for (int mt = 0; mt < 4; ++mt)
        #pragma unroll
        for (int j = 0; j < 4; ++j)
            acc[mt][j] = kh ? bias2[mt*16 + qq*4 + j] : 0.f;

    float omy = omb[pix];
    float omx = omb[(size_t)HW + pix];
    float omm = omb[(size_t)18*HW + pix];
    __syncthreads();                             // tile ready

    #pragma unroll
    for (int p = 0; p < 9; ++p) {
        // A-frags for my K-half (tiny, L1/L2-hot)
        short8 afr[4];
        #pragma unroll
        for (int mt = 0; mt < 4; ++mt)
            afr[mt] = *(const short8*)(w2p + (size_t)p*4096 + (mt*16 + nn)*64);

        // bilinear corner weights for my pixel
        float mv = 1.f / (1.f + expf(-omm));
        float ysv = (float)(y - 1 + p/3) + omy;
        float xsv = (float)(x - 1 + p%3) + omx;
        float y0f = floorf(ysv), x0f = floorf(xsv);
        float ly = ysv - y0f, lx = xsv - x0f;
        int y0 = (int)y0f, x0i = (int)x0f;
        int y1 = y0 + 1, x1 = x0i + 1;
        float vy0 = (y0 >= 0 && y0 < HH) ? 1.f : 0.f;
        float vy1 = (y1 >= 0 && y1 < HH) ? 1.f : 0.f;
        float vx0 = (x0i >= 0 && x0i < WW) ? 1.f : 0.f;
        float vx1 = (x1 >= 0 && x1 < WW) ? 1.f : 0.f;
        float w00 = (1.f-ly)*(1.f-lx)*mv * vy0*vx0;
        float w01 = (1.f-ly)*lx      *mv * vy0*vx1;
        float w10 = ly      *(1.f-lx)*mv * vy1*vx0;
        float w11 = ly      *lx      *mv * vy1*vx1;
        int y0c = min(max(y0,0),HH-1), y1c = min(max(y1,0),HH-1);
        int x0c = min(max(x0i,0),WW-1), x1c = min(max(x1,0),WW-1);

        // prefetch next p's om
        if (p < 8) {
            omy = omb[(size_t)(2*p+2)*HW + pix];
            omx = omb[(size_t)(2*p+3)*HW + pix];
            omm = omb[(size_t)(19+p )*HW + pix];
        }

        // gather 4 corners: LDS fast path, global fallback (rare)
        short8 c00, c01, c10, c11;
        {
            int sy0 = y0c - ybase, sy1 = y1c - ybase;
            int sx0 = x0c - xbase, sx1 = x1c - xbase;
            bool allin = ((unsigned)sy0 < 5) & ((unsigned)sy1 < 5) &
                         ((unsigned)sx0 < 36) & ((unsigned)sx1 < 36);
            if (allin) {
                int p00 = sy0*36 + sx0, p01 = sy0*36 + sx1;
                int p10 = sy1*36 + sx0, p11 = sy1*36 + sx1;
                c00 = *(const short8*)(gt + ((p00*128 + cob) ^ ((p00&7)<<4)));
                c01 = *(const short8*)(gt + ((p01*128 + cob) ^ ((p01&7)<<4)));
                c10 = *(const short8*)(gt + ((p10*128 + cob) ^ ((p10&7)<<4)));
                c11 = *(const short8*)(gt + ((p11*128 + cob) ^ ((p11&7)<<4)));
            } else {
                int i00 = y0c*WW + x0c, i01 = y0c*WW + x1c;
                int i10 = y1c*WW + x0c, i11 = y1c*WW + x1c;
                c00 = *(const short8*)(Fb + (size_t)i00*64 + co);
                c01 = *(const short8*)(Fb + (size_t)i01*64 + co);
                c10 = *(const short8*)(Fb + (size_t)i10*64 + co);
                c11 = *(const short8*)(Fb + (size_t)i11*64 + co);
            }
        }

        // pack: float2 weighted sum (v_pk_fma_f32) + v_cvt_pk_bf16_f32
        uint4v u00 = __builtin_bit_cast(uint4v, c00);
        uint4v u01 = __builtin_bit_cast(uint4v, c01);
        uint4v u10 = __builtin_bit_cast(uint4v, c10);
        uint4v u11 = __builtin_bit_cast(uint4v, c11);
        unsigned int pw[4];
        #pragma unroll
        for (int jp = 0; jp < 4; ++jp) {
            f32x2 A = bfpair(u00[jp]);
            f32x2 B = bfpair(u01[jp]);
            f32x2 C = bfpair(u10[jp]);
            f32x2 D = bfpair(u11[jp]);
            f32x2 r = A*w00 + B*w01 + C*w10 + D*w11;
            pw[jp] = cvtpk_bf16(r[0], r[1]);
        }
        uint4v u4 = {pw[0], pw[1], pw[2], pw[3]};
        short8 bfr = __builtin_bit_cast(short8, u4);

        // MFMA (my K-half only)
        #pragma unroll
        for (int mt = 0; mt < 4; ++mt)
            acc[mt] = __builtin_amdgcn_mfma_f32_16x16x32_bf16(
                          afr[mt], bfr, acc[mt], 0, 0, 0);
    }

    // combine wave-pair partials; reduction buffer ALIASES gtile, so first
    // ensure all waves finished their LDS gathers.
    __syncthreads();
    float* red = (float*)gtile;
    if (kh == 0) {
        #pragma unroll
        for (int mt = 0; mt < 4; ++mt)
            #pragma unroll
            for (int j = 0; j < 4; ++j)
                red[(mt*4 + j)*128 + strip*64 + lane] = acc[mt][j];
    }
    __syncthreads();
    if (kh == 1) {
        float* outp = out + (size_t)b*COUT*HW + (size_t)y*WW + px0 + nn;
        #pragma unroll
        for (int mt = 0; mt < 4; ++mt)
            #pragma unroll
            for (int j = 0; j < 4; ++j)
                outp[(size_t)(mt*16 + qq*4 + j)*HW] =
                    acc[mt][j] + red[(mt*4 + j)*128 + strip*64 + lane];
    }
}

// ---------------------------------------------------------------------------
extern "C" void kernel_launch(void* const* d_in, const int* in_sizes, int n_in,
                              void* d_out, int out_size, void* d_ws, size_t ws_size,
                              hipStream_t stream) {
    const float* input_feat = (const float*)d_in[0];
    const float* inter      = (const float*)d_in[1];
    const float* fea        = (const float*)d_in[2];
    const float* weight     = (const float*)d_in[3];
    const float* bias       = (const float*)d_in[4];
    const float* com_w      = (const float*)d_in[5];
    const float* com_b      = (const float*)d_in[6];
    const float* c1w        = (const float*)d_in[7];
    const float* c2w        = (const float*)d_in[8];
    float* out = (float*)d_out;

    float* ws    = (float*)d_ws;
    float* bias2 = ws + 256;                               // 64 (in pad area)
    unsigned short* w2b = (unsigned short*)(ws + 512);     // 147456 us
    float* om    = ws + 512 + 73728;                       // 1769472 f
    unsigned short* wk2 = (unsigned short*)(om + 1769472); // 20480 us
    unsigned short* fT  = wk2 + 20480;                     // 4194304 us

    prep_kernel<<<81, 256, 0, stream>>>(com_w, c2w, bias, wk2, bias2);
    main2_kernel<<<2112, 256, 0, stream>>>(input_feat, inter, wk2, com_b,
                                           weight, c2w, c1w, fea, om, w2b, fT);
    dcn_main_kernel<<<2048, 256, 0, stream>>>(fT, w2b, bias2, om, out);
}